// Round 10
// baseline (159.205 us; speedup 1.0000x reference)
//
#include <hip/hip_runtime.h>
#include <stdint.h>

typedef unsigned long long u64;
typedef unsigned int u32;

#define BATCH   8
#define TOTAL   21824
#define NCLS    80
#define NDET    100
#define IMGSZ   1024.0f
#define STHR    0.2f
#define NMST    0.6f
#define NBUCK   2048        /* monotone score buckets */
#define KGLOB   1000        /* global top-K prefix (== min per-level k) */
#define NLOC    22          /* ceil(TOTAL/1024) per-thread cached scores */

__device__ __forceinline__ float sigm(float x) { return 1.0f / (1.0f + expf(-x)); }

// Order-preserving map: ascending km == descending score.
__device__ __forceinline__ u32 mapKm(float s) {
    u32 u = __float_as_uint(s);
    u32 m = u ^ ((u & 0x80000000u) ? 0xFFFFFFFFu : 0x80000000u);
    return ~m;
}
// Composite key: ascending u64 == (score desc, anchor idx asc) — equals the
// reference's merged candidate order for any prefix <= 1000.
__device__ __forceinline__ u64 makeKey(float s, u32 idx) {
    return (((u64)mapKm(s)) << 32) | (u64)idx;
}

// Monotone bucket: descending score -> ascending bucket. Valid scores (>0.2)
// land in [0,2016); masked -1.0 would clamp to 2047 (never inserted).
__device__ __forceinline__ int bucketOf(float s) {
    int b = (int)(__fmul_rn(__fsub_rn(1.0f, s), 2520.0f));
    return b > (NBUCK - 1) ? (NBUCK - 1) : b;
}

// Bit-exact IoU suppression test (no FMA contraction).
__device__ __forceinline__ bool suppress(float4 a, float4 c) {
    float aa = __fmul_rn(fmaxf(__fsub_rn(a.z, a.x), 0.f), fmaxf(__fsub_rn(a.w, a.y), 0.f));
    float ac = __fmul_rn(fmaxf(__fsub_rn(c.z, c.x), 0.f), fmaxf(__fsub_rn(c.w, c.y), 0.f));
    float ltx = fmaxf(a.x, c.x), lty = fmaxf(a.y, c.y);
    float rbx = fminf(a.z, c.z), rby = fminf(a.w, c.w);
    float iw = fmaxf(__fsub_rn(rbx, ltx), 0.f), ih = fmaxf(__fsub_rn(rby, lty), 0.f);
    float inter = __fmul_rn(iw, ih);
    float uni = __fsub_rn(__fadd_rn(aa, ac), inter);
    float iou = __fdiv_rn(inter, fmaxf(uni, 1e-9f));
    return iou > NMST;
}

// ---------------- Kernel 1: coalesced score/argmax ----------------
__global__ __launch_bounds__(256) void score_kernel(
        const float* __restrict__ logits, const float* __restrict__ ctr,
        float* __restrict__ mscore, int* __restrict__ mlabel) {
    const int b = blockIdx.y;
    const int tid = threadIdx.x;
    const int wave = tid >> 6, lane = tid & 63;
    const int g = lane >> 2, j = lane & 3;
    const int rowBase = blockIdx.x * 256 + wave * 64;
#pragma unroll
    for (int t = 0; t < 4; t++) {
        int r = rowBase + 16 * t + g;
        bool valid = r < TOTAL;
        float best = -1e30f; int bi = 0;
        if (valid) {
            const float* rowp = logits + ((size_t)b * TOTAL + r) * NCLS + j * 4;
#pragma unroll
            for (int u = 0; u < 5; u++) {
                float4 v = *(const float4*)(rowp + u * 16);
                int c0 = u * 16 + j * 4;
                if (v.x > best) { best = v.x; bi = c0; }
                if (v.y > best) { best = v.y; bi = c0 + 1; }
                if (v.z > best) { best = v.z; bi = c0 + 2; }
                if (v.w > best) { best = v.w; bi = c0 + 3; }
            }
        }
        // merge 4 lanes of one row: max, tie -> lowest class index
#pragma unroll
        for (int off = 1; off <= 2; off <<= 1) {
            float ob = __shfl_xor(best, off);
            int obi = __shfl_xor(bi, off);
            if (ob > best || (ob == best && obi < bi)) { best = ob; bi = obi; }
        }
        if (valid && j == 0) {
            float c = ctr[(size_t)b * TOTAL + r];
            float sc = sqrtf(sigm(best) * sigm(c));
            float msc = (sc > STHR) ? sc : -1.0f;
            mscore[(size_t)b * TOTAL + r] = msc;
            mlabel[(size_t)b * TOTAL + r] = bi;
        }
    }
}

// ---------------- Kernel 2: histogram -> global top-K gather -> sort -> windowed NMS -> emit ----------------
__global__ __launch_bounds__(1024) void nms_kernel(
        const float* __restrict__ mscore, const int* __restrict__ mlabel,
        const float* __restrict__ anchors, const float* __restrict__ reg,
        float* __restrict__ out) {
    __shared__ u32 hist[NBUCK];
    __shared__ u64 keys[2048];
    __shared__ u64 skey[2048];
    __shared__ u32 waveSum[16], waveOff[16];
    __shared__ u32 sh_B;
    __shared__ int sh_cnt, s_count;
    __shared__ int accI[NDET];
    __shared__ float4 accB[NDET];   // class-offset boxes of accepted
    __shared__ float4 accR[NDET];   // raw (clamped) boxes of accepted
    __shared__ int wIdx[64];
    __shared__ float4 wb[64], wraw[64];
    __shared__ u64 wsup[64];
    __shared__ u32 s_rej32[2];

    const int b = blockIdx.x, tid = threadIdx.x;
    const int wave = tid >> 6, lane = tid & 63;
    const float* ms = mscore + (size_t)b * TOTAL;

    // Pass 0: zero histogram; sentinel boundary = end of valid-score region.
    hist[tid] = 0; hist[tid + 1024] = 0;
    if (tid == 0) { sh_cnt = 0; s_count = 0; sh_B = 2015u; }
    __syncthreads();

    // Pass 1: histogram of VALID scores only (invalid would all serialize on
    // one bucket — and their counts are never used). Cache scores in regs.
    float sv[NLOC];
    {
        int nl = 0;
        for (int i = tid; i < TOTAL; i += 1024) {
            float s0 = ms[i];
            sv[nl++] = s0;
            if (s0 > STHR) atomicAdd(&hist[bucketOf(s0)], 1u);
        }
    }
    __syncthreads();

    // Scan: thread t owns buckets 2t, 2t+1; find bucket of the KGLOB-th valid.
    u32 h0 = hist[2 * tid], h1 = hist[2 * tid + 1];
    u32 s = h0 + h1;
    u32 incl = s;
    for (int o = 1; o < 64; o <<= 1) {
        u32 t2 = (u32)__shfl_up((int)incl, o);
        if (lane >= o) incl += t2;
    }
    if (lane == 63) waveSum[wave] = incl;
    __syncthreads();
    if (tid == 0) {
        u32 acc = 0;
#pragma unroll
        for (int w = 0; w < 16; w++) { waveOff[w] = acc; acc += waveSum[w]; }
    }
    __syncthreads();
    {
        u32 E = waveOff[wave] + incl - s;
        if (E < KGLOB && KGLOB <= E + h0) sh_B = (u32)(2 * tid);
        else if (E + h0 < KGLOB && KGLOB <= E + h0 + h1) sh_B = (u32)(2 * tid + 1);
    }
    __syncthreads();
    const int Bstar = (int)sh_B;   // sentinel 2015 => fewer than KGLOB valid => take all

    // Pass 2: gather downward-closed superset of global top-K (bucket <= Bstar),
    // wave-aggregated append.
    {
        int nl = 0;
        for (int i = tid; i < TOTAL; i += 1024) {
            float s0 = sv[nl++];
            bool take = (s0 > STHR) && (bucketOf(s0) <= Bstar);
            u64 mk = __ballot(take);
            if (mk) {
                int leader = __builtin_ctzll(mk);
                int base = 0;
                if (lane == leader) base = atomicAdd(&sh_cnt, (int)__popcll(mk));
                base = __shfl(base, leader);
                if (take) {
                    int pos = base + (int)__popcll(mk & ((1ull << lane) - 1ull));
                    if (pos < 2048) keys[pos] = makeKey(s0, (u32)i);
                }
            }
        }
    }
    __syncthreads();
    int m = sh_cnt; if (m > 2048) m = 2048;

    // Sort by rank-by-counting (broadcast LDS reads; keys distinct)
    {
        u64 k0 = (tid < m) ? keys[tid] : ~0ull;
        u64 k1 = (tid + 1024 < m) ? keys[tid + 1024] : ~0ull;
        int r0 = 0, r1 = 0;
        for (int f = 0; f < m; f++) {
            u64 kf = keys[f];
            r0 += (kf < k0);
            r1 += (kf < k1);
        }
        if (tid < m) skey[r0] = k0;
        if (tid + 1024 < m) skey[r1] = k1;
    }
    __syncthreads();

    // Windowed greedy NMS over the sorted prefix
    int count = 0, E = 0;
    while (true) {
        int take = m - E; if (take > 64) take = 64;
        if (take <= 0) break;

        if (tid < take) {
            int idx = (int)(skey[E + tid] & 0xFFFFFFFFu);
            float4 a = ((const float4*)anchors)[idx];
            float4 r = ((const float4*)reg)[(size_t)b * TOTAL + idx];
            float cx = (a.x + a.z) * 0.5f;
            float cy = (a.y + a.w) * 0.5f;
            float x1 = fminf(fmaxf(cx - r.x, 0.0f), IMGSZ);
            float y1 = fminf(fmaxf(cy - r.y, 0.0f), IMGSZ);
            float x2 = fminf(fmaxf(cx + r.z, 0.0f), IMGSZ);
            float y2 = fminf(fmaxf(cy + r.w, 0.0f), IMGSZ);
            float4 raw = make_float4(x1, y1, x2, y2);
            float off = (float)mlabel[(size_t)b * TOTAL + idx] * (IMGSZ + 1.0f);
            float4 ob = make_float4(__fadd_rn(x1, off), __fadd_rn(y1, off),
                                    __fadd_rn(x2, off), __fadd_rn(y2, off));
            wraw[tid] = raw; wb[tid] = ob; wIdx[tid] = idx;
        }
        if (tid < 2) s_rej32[tid] = 0;
        __syncthreads();

        // reject phase: window element (lane) vs accepted set (strided by wave)
        {
            bool rej = false;
            if (lane < take) {
                for (int s2 = wave; s2 < count; s2 += 16) {
                    if (suppress(accB[s2], wb[lane])) { rej = true; break; }
                }
            }
            u64 mask = __ballot(rej);
            if (lane == 0 && mask) {
                u32 lo = (u32)mask, hi = (u32)(mask >> 32);
                if (lo) atomicOr(&s_rej32[0], lo);
                if (hi) atomicOr(&s_rej32[1], hi);
            }
        }
        // intra-window pair masks: wsup[rr] bit c == (rr suppresses c), c>rr
        for (int rr = wave; rr < take; rr += 16) {
            bool sp = false;
            if (lane < take && lane > rr) sp = suppress(wb[rr], wb[lane]);
            u64 mask = __ballot(sp);
            if (lane == 0) wsup[rr] = mask;
        }
        __syncthreads();

        // greedy resolve within window (wave 0, registers only)
        if (wave == 0) {
            u64 supr = (lane < take) ? wsup[lane] : 0;
            u64 rejM = (u64)s_rej32[0] | ((u64)s_rej32[1] << 32);
            u64 aliveM = ((take >= 64) ? ~0ull : ((1ull << take) - 1ull)) & ~rejM;
            u64 accM = 0;
            for (int rr = 0; rr < take; rr++) {
                if ((aliveM >> rr) & 1) {
                    accM |= 1ull << rr;
                    u64 sr = __shfl(supr, rr);
                    aliveM &= ~sr;
                }
            }
            int na = __popcll(accM);
            int space = NDET - count;
            int takeA = na < space ? na : space;
            if (lane < take && ((accM >> lane) & 1)) {
                int pos = __popcll(accM & ((1ull << lane) - 1ull));
                if (pos < takeA) {
                    accI[count + pos] = wIdx[lane];
                    accB[count + pos] = wb[lane];
                    accR[count + pos] = wraw[lane];
                }
            }
            if (lane == 0) s_count = count + takeA;
        }
        __syncthreads();
        count = s_count;
        E += take;
        if (count >= NDET) break;
    }
    __syncthreads();

    // emit top-100
    for (int s2 = tid; s2 < NDET; s2 += 1024) {
        float4 bxv = make_float4(0.f, 0.f, 0.f, 0.f);
        float scv = 0.0f, lbv = -1.0f;
        if (s2 < count) {
            int idx = accI[s2];
            bxv = accR[s2];
            scv = ms[idx];
            lbv = (float)mlabel[(size_t)b * TOTAL + idx];
        }
        ((float4*)out)[b * NDET + s2] = bxv;                                  // boxes [0,3200)
        out[BATCH * NDET * 4 + b * NDET + s2] = scv;                          // scores [3200,4000)
        out[BATCH * NDET * 4 + BATCH * NDET + b * NDET + s2] = lbv;           // labels [4000,4800)
    }
}

extern "C" void kernel_launch(void* const* d_in, const int* in_sizes, int n_in,
                              void* d_out, int out_size, void* d_ws, size_t ws_size,
                              hipStream_t stream) {
    (void)in_sizes; (void)n_in; (void)out_size; (void)ws_size;
    const float* logits  = (const float*)d_in[0];
    const float* reg     = (const float*)d_in[1];
    const float* ctr     = (const float*)d_in[2];
    const float* anchors = (const float*)d_in[3];
    float* out = (float*)d_out;

    char* ws = (char*)d_ws;
    size_t off = 0;
    auto alloc = [&](size_t bytes) -> void* {
        off = (off + 255) & ~(size_t)255;
        void* p = ws + off;
        off += bytes;
        return p;
    };
    float* mscore = (float*)alloc((size_t)BATCH * TOTAL * 4);
    int*   mlabel = (int*)  alloc((size_t)BATCH * TOTAL * 4);

    score_kernel<<<dim3((TOTAL + 255) / 256, BATCH), 256, 0, stream>>>(logits, ctr, mscore, mlabel);
    nms_kernel<<<BATCH, 1024, 0, stream>>>(mscore, mlabel, anchors, reg, out);
}

// Round 11
// 144.498 us; speedup vs baseline: 1.1018x; 1.1018x over previous
//
#include <hip/hip_runtime.h>
#include <stdint.h>

typedef unsigned long long u64;
typedef unsigned int u32;

#define BATCH   8
#define TOTAL   21824
#define NCLS    80
#define NDET    100
#define IMGSZ   1024.0f
#define STHR    0.2f
#define NMST    0.6f
#define NBUCK   2048        /* monotone score buckets */
#define BMAX    2015        /* last bucket reachable by valid scores (clamped) */
#define KGLOB   1000        /* global top-K prefix (== min per-level k) */
#define NLOC    22          /* ceil(TOTAL/1024) per-thread cached scores */

__device__ __forceinline__ float sigm(float x) { return 1.0f / (1.0f + expf(-x)); }

// Order-preserving map: ascending km == descending score.
__device__ __forceinline__ u32 mapKm(float s) {
    u32 u = __float_as_uint(s);
    u32 m = u ^ ((u & 0x80000000u) ? 0xFFFFFFFFu : 0x80000000u);
    return ~m;
}
// Composite key: ascending u64 == (score desc, anchor idx asc) — equals the
// reference's merged candidate order for any prefix <= 1000.
__device__ __forceinline__ u64 makeKey(float s, u32 idx) {
    return (((u64)mapKm(s)) << 32) | (u64)idx;
}

// Monotone bucket for VALID scores (>0.2): clamped to [0, BMAX]. Weakly
// monotone (score desc -> bucket asc); intra-bucket order fixed by full key.
__device__ __forceinline__ int bucketOfV(float s) {
    int b = (int)(__fmul_rn(__fsub_rn(1.0f, s), 2520.0f));
    return b > BMAX ? BMAX : b;
}

// Bit-exact IoU suppression test (no FMA contraction).
__device__ __forceinline__ bool suppress(float4 a, float4 c) {
    float aa = __fmul_rn(fmaxf(__fsub_rn(a.z, a.x), 0.f), fmaxf(__fsub_rn(a.w, a.y), 0.f));
    float ac = __fmul_rn(fmaxf(__fsub_rn(c.z, c.x), 0.f), fmaxf(__fsub_rn(c.w, c.y), 0.f));
    float ltx = fmaxf(a.x, c.x), lty = fmaxf(a.y, c.y);
    float rbx = fminf(a.z, c.z), rby = fminf(a.w, c.w);
    float iw = fmaxf(__fsub_rn(rbx, ltx), 0.f), ih = fmaxf(__fsub_rn(rby, lty), 0.f);
    float inter = __fmul_rn(iw, ih);
    float uni = __fsub_rn(__fadd_rn(aa, ac), inter);
    float iou = __fdiv_rn(inter, fmaxf(uni, 1e-9f));
    return iou > NMST;
}

// ---------------- Kernel 1: coalesced score/argmax ----------------
__global__ __launch_bounds__(256) void score_kernel(
        const float* __restrict__ logits, const float* __restrict__ ctr,
        float* __restrict__ mscore, int* __restrict__ mlabel) {
    const int b = blockIdx.y;
    const int tid = threadIdx.x;
    const int wave = tid >> 6, lane = tid & 63;
    const int g = lane >> 2, j = lane & 3;
    const int rowBase = blockIdx.x * 256 + wave * 64;
#pragma unroll
    for (int t = 0; t < 4; t++) {
        int r = rowBase + 16 * t + g;
        bool valid = r < TOTAL;
        float best = -1e30f; int bi = 0;
        if (valid) {
            const float* rowp = logits + ((size_t)b * TOTAL + r) * NCLS + j * 4;
#pragma unroll
            for (int u = 0; u < 5; u++) {
                float4 v = *(const float4*)(rowp + u * 16);
                int c0 = u * 16 + j * 4;
                if (v.x > best) { best = v.x; bi = c0; }
                if (v.y > best) { best = v.y; bi = c0 + 1; }
                if (v.z > best) { best = v.z; bi = c0 + 2; }
                if (v.w > best) { best = v.w; bi = c0 + 3; }
            }
        }
        // merge 4 lanes of one row: max, tie -> lowest class index
#pragma unroll
        for (int off = 1; off <= 2; off <<= 1) {
            float ob = __shfl_xor(best, off);
            int obi = __shfl_xor(bi, off);
            if (ob > best || (ob == best && obi < bi)) { best = ob; bi = obi; }
        }
        if (valid && j == 0) {
            float c = ctr[(size_t)b * TOTAL + r];
            float sc = sqrtf(sigm(best) * sigm(c));
            float msc = (sc > STHR) ? sc : -1.0f;
            mscore[(size_t)b * TOTAL + r] = msc;
            mlabel[(size_t)b * TOTAL + r] = bi;
        }
    }
}

// ---------------- Kernel 2: histogram radix-scatter sort -> windowed NMS -> emit ----------------
__global__ __launch_bounds__(1024) void nms_kernel(
        const float* __restrict__ mscore, const int* __restrict__ mlabel,
        const float* __restrict__ anchors, const float* __restrict__ reg,
        float* __restrict__ out) {
    __shared__ u32 hist[NBUCK];     // counts, then scatter cursors (exclusive bases)
    __shared__ u64 skey[2048];      // bucket-radix sorted keys
    __shared__ u32 waveSum[16], waveOff[16];
    __shared__ u32 sh_B, sh_m;
    __shared__ int s_count;
    __shared__ int accI[NDET];
    __shared__ float4 accB[NDET];   // class-offset boxes of accepted
    __shared__ float4 accR[NDET];   // raw (clamped) boxes of accepted
    __shared__ int wIdx[64];
    __shared__ float4 wb[64], wraw[64];
    __shared__ u64 wsup[64];
    __shared__ u32 s_rej32[2];

    const int b = blockIdx.x, tid = threadIdx.x;
    const int wave = tid >> 6, lane = tid & 63;
    const float* ms = mscore + (size_t)b * TOTAL;

    // Pass 0: zero histogram; sentinel boundary = end of valid-score region.
    hist[tid] = 0; hist[tid + 1024] = 0;
    if (tid == 0) { s_count = 0; sh_B = (u32)BMAX; }
    __syncthreads();

    // Pass 1: histogram of VALID scores only; cache scores in registers.
    float sv[NLOC];
    {
        int nl = 0;
        for (int i = tid; i < TOTAL; i += 1024) {
            float s0 = ms[i];
            sv[nl++] = s0;
            if (s0 > STHR) atomicAdd(&hist[bucketOfV(s0)], 1u);
        }
    }
    __syncthreads();

    // Scan: thread t owns buckets 2t, 2t+1.
    u32 h0 = hist[2 * tid], h1 = hist[2 * tid + 1];
    u32 s = h0 + h1;
    u32 incl = s;
    for (int o = 1; o < 64; o <<= 1) {
        u32 t2 = (u32)__shfl_up((int)incl, o);
        if (lane >= o) incl += t2;
    }
    if (lane == 63) waveSum[wave] = incl;
    __syncthreads();
    if (tid == 0) {
        u32 acc = 0;
#pragma unroll
        for (int w = 0; w < 16; w++) { waveOff[w] = acc; acc += waveSum[w]; }
        sh_m = acc;                       // default: all valid (if < KGLOB valid)
    }
    __syncthreads();
    const u32 E = waveOff[wave] + incl - s;   // keys in buckets < 2*tid
    // locate boundary bucket of the KGLOB-th valid; record inclusive count m
    if (E < KGLOB && KGLOB <= E + h0)            { sh_B = (u32)(2 * tid);     sh_m = E + h0; }
    else if (E + h0 < KGLOB && KGLOB <= E + h0 + h1) { sh_B = (u32)(2 * tid + 1); sh_m = E + h0 + h1; }
    // overwrite hist with exclusive bases (scatter cursors)
    hist[2 * tid] = E;
    hist[2 * tid + 1] = E + h0;
    __syncthreads();
    const int Bstar = (int)sh_B;

    // Pass 2: radix scatter — key goes directly to its bucket's slot range.
    {
        int nl = 0;
        for (int i = tid; i < TOTAL; i += 1024) {
            float s0 = sv[nl++];
            if (s0 > STHR) {
                int bk = bucketOfV(s0);
                if (bk <= Bstar) {
                    int pos = (int)atomicAdd(&hist[bk], 1u);
                    if (pos < 2048) skey[pos] = makeKey(s0, (u32)i);
                }
            }
        }
    }
    __syncthreads();

    // Cleanup: insertion-sort each bucket's tiny segment (thread owns 2 buckets).
#pragma unroll
    for (int q = 0; q < 2; q++) {
        int bk = 2 * tid + q;
        u32 cnt = q ? h1 : h0;
        if (bk <= Bstar && cnt > 1) {
            int lo = (int)(q ? (E + h0) : E);
            int hi = lo + (int)cnt; if (hi > 2048) hi = 2048;
            for (int i2 = lo + 1; i2 < hi; i2++) {
                u64 key = skey[i2];
                int j2 = i2 - 1;
                while (j2 >= lo && skey[j2] > key) { skey[j2 + 1] = skey[j2]; j2--; }
                skey[j2 + 1] = key;
            }
        }
    }
    __syncthreads();
    int m = (int)sh_m; if (m > 2048) m = 2048;

    // Windowed greedy NMS over the sorted prefix
    int count = 0, Ew = 0;
    while (true) {
        int take = m - Ew; if (take > 64) take = 64;
        if (take <= 0) break;

        if (tid < take) {
            int idx = (int)(skey[Ew + tid] & 0xFFFFFFFFu);
            float4 a = ((const float4*)anchors)[idx];
            float4 r = ((const float4*)reg)[(size_t)b * TOTAL + idx];
            float cx = (a.x + a.z) * 0.5f;
            float cy = (a.y + a.w) * 0.5f;
            float x1 = fminf(fmaxf(cx - r.x, 0.0f), IMGSZ);
            float y1 = fminf(fmaxf(cy - r.y, 0.0f), IMGSZ);
            float x2 = fminf(fmaxf(cx + r.z, 0.0f), IMGSZ);
            float y2 = fminf(fmaxf(cy + r.w, 0.0f), IMGSZ);
            float4 raw = make_float4(x1, y1, x2, y2);
            float off = (float)mlabel[(size_t)b * TOTAL + idx] * (IMGSZ + 1.0f);
            float4 ob = make_float4(__fadd_rn(x1, off), __fadd_rn(y1, off),
                                    __fadd_rn(x2, off), __fadd_rn(y2, off));
            wraw[tid] = raw; wb[tid] = ob; wIdx[tid] = idx;
        }
        if (tid < 2) s_rej32[tid] = 0;
        __syncthreads();

        // reject phase: window element (lane) vs accepted set (strided by wave)
        {
            bool rej = false;
            if (lane < take) {
                for (int s2 = wave; s2 < count; s2 += 16) {
                    if (suppress(accB[s2], wb[lane])) { rej = true; break; }
                }
            }
            u64 mask = __ballot(rej);
            if (lane == 0 && mask) {
                u32 lo = (u32)mask, hi = (u32)(mask >> 32);
                if (lo) atomicOr(&s_rej32[0], lo);
                if (hi) atomicOr(&s_rej32[1], hi);
            }
        }
        // intra-window pair masks: wsup[rr] bit c == (rr suppresses c), c>rr
        for (int rr = wave; rr < take; rr += 16) {
            bool sp = false;
            if (lane < take && lane > rr) sp = suppress(wb[rr], wb[lane]);
            u64 mask = __ballot(sp);
            if (lane == 0) wsup[rr] = mask;
        }
        __syncthreads();

        // greedy resolve within window (wave 0, registers only)
        if (wave == 0) {
            u64 supr = (lane < take) ? wsup[lane] : 0;
            u64 rejM = (u64)s_rej32[0] | ((u64)s_rej32[1] << 32);
            u64 aliveM = ((take >= 64) ? ~0ull : ((1ull << take) - 1ull)) & ~rejM;
            u64 accM = 0;
            for (int rr = 0; rr < take; rr++) {
                if ((aliveM >> rr) & 1) {
                    accM |= 1ull << rr;
                    u64 sr = __shfl(supr, rr);
                    aliveM &= ~sr;
                }
            }
            int na = __popcll(accM);
            int space = NDET - count;
            int takeA = na < space ? na : space;
            if (lane < take && ((accM >> lane) & 1)) {
                int pos = __popcll(accM & ((1ull << lane) - 1ull));
                if (pos < takeA) {
                    accI[count + pos] = wIdx[lane];
                    accB[count + pos] = wb[lane];
                    accR[count + pos] = wraw[lane];
                }
            }
            if (lane == 0) s_count = count + takeA;
        }
        __syncthreads();
        count = s_count;
        Ew += take;
        if (count >= NDET) break;
    }
    __syncthreads();

    // emit top-100
    for (int s2 = tid; s2 < NDET; s2 += 1024) {
        float4 bxv = make_float4(0.f, 0.f, 0.f, 0.f);
        float scv = 0.0f, lbv = -1.0f;
        if (s2 < count) {
            int idx = accI[s2];
            bxv = accR[s2];
            scv = ms[idx];
            lbv = (float)mlabel[(size_t)b * TOTAL + idx];
        }
        ((float4*)out)[b * NDET + s2] = bxv;                                  // boxes [0,3200)
        out[BATCH * NDET * 4 + b * NDET + s2] = scv;                          // scores [3200,4000)
        out[BATCH * NDET * 4 + BATCH * NDET + b * NDET + s2] = lbv;           // labels [4000,4800)
    }
}

extern "C" void kernel_launch(void* const* d_in, const int* in_sizes, int n_in,
                              void* d_out, int out_size, void* d_ws, size_t ws_size,
                              hipStream_t stream) {
    (void)in_sizes; (void)n_in; (void)out_size; (void)ws_size;
    const float* logits  = (const float*)d_in[0];
    const float* reg     = (const float*)d_in[1];
    const float* ctr     = (const float*)d_in[2];
    const float* anchors = (const float*)d_in[3];
    float* out = (float*)d_out;

    char* ws = (char*)d_ws;
    size_t off = 0;
    auto alloc = [&](size_t bytes) -> void* {
        off = (off + 255) & ~(size_t)255;
        void* p = ws + off;
        off += bytes;
        return p;
    };
    float* mscore = (float*)alloc((size_t)BATCH * TOTAL * 4);
    int*   mlabel = (int*)  alloc((size_t)BATCH * TOTAL * 4);

    score_kernel<<<dim3((TOTAL + 255) / 256, BATCH), 256, 0, stream>>>(logits, ctr, mscore, mlabel);
    nms_kernel<<<BATCH, 1024, 0, stream>>>(mscore, mlabel, anchors, reg, out);
}